// Round 1
// baseline (4125.132 us; speedup 1.0000x reference)
//
#include <hip/hip_runtime.h>

// AutoregressiveForecaster: 2-layer LSTM(H=64) + MLP head, 20 autoregressive
// steps over a circular 24-window. B=8192 fp32.
//
// Design (round 1):
//  - 256 blocks x 512 threads (8 waves). Each wave owns 4 batch elements;
//    lane j owns hidden unit j (gates i,f,g,o = rows g*64+j of each W).
//  - Weights packed to f16x2 in LDS ([k2][j][g], 32KB each x3 = 96KB);
//    inner product via v_dot2_f32_f16 (fp32 accumulate).
//  - h1/h2 staged per-wave in LDS as f16 pairs [k2][mb] (broadcast b128 read
//    serves all 4 batch elems). No cross-wave sharing -> no barriers in loop.
//  - 24-slot circular window in LDS; MLP head via 32-lane butterfly reduce.

typedef _Float16 f16x2 __attribute__((ext_vector_type(2)));

#define NBLK  256
#define NTHR  512
#define BPW   4     // batch per wave
#define BPB   32    // batch per block
#define TWIN  24
#define HSTR  36    // padded row stride (uints) for h staging

// LDS byte offsets
#define OFF_PW0    0        // [32][64][4] uint = 32768
#define OFF_PIH1   32768
#define OFF_PHH1   65536
#define OFF_PW1M   98304    // [32][32] uint = 4096
#define OFF_H1P    102400   // [32][36] uint = 4608
#define OFF_H2P    107008
#define OFF_WIN    111616   // [24][32] float = 3072
#define OFF_W2     114688   // 32 floats
#define OFF_B1S    114816   // 32 floats
#define SMEM_BYTES 114944

union H2U { unsigned u; f16x2 v; _Float16 h[2]; };

__device__ __forceinline__ float sigm(float x) {
  float e = __builtin_amdgcn_exp2f(-1.44269504089f * x);
  return __builtin_amdgcn_rcpf(1.0f + e);
}
__device__ __forceinline__ float tanh_(float x) {
  float e = __builtin_amdgcn_exp2f(-2.88539008178f * x);
  return __builtin_amdgcn_rcpf(1.0f + e) * 2.0f - 1.0f;
}
__device__ __forceinline__ unsigned pack2(float lo, float hi) {
  f16x2 v = { (_Float16)lo, (_Float16)hi };
  return __builtin_bit_cast(unsigned, v);
}
__device__ __forceinline__ float dot2(unsigned a, unsigned b, float c) {
#if __has_builtin(__builtin_amdgcn_fdot2)
  return __builtin_amdgcn_fdot2(__builtin_bit_cast(f16x2, a),
                                __builtin_bit_cast(f16x2, b), c, false);
#else
  H2U ua, ub; ua.u = a; ub.u = b;
  return fmaf((float)ua.h[1], (float)ub.h[1],
              fmaf((float)ua.h[0], (float)ub.h[0], c));
#endif
}

__global__ __launch_bounds__(NTHR, 1) void lstm_forecast(
    const float* __restrict__ x,
    const float* __restrict__ Wih0, const float* __restrict__ Whh0,
    const float* __restrict__ bih0, const float* __restrict__ bhh0,
    const float* __restrict__ Wih1, const float* __restrict__ Whh1,
    const float* __restrict__ bih1, const float* __restrict__ bhh1,
    const float* __restrict__ W1,   const float* __restrict__ b1,
    const float* __restrict__ W2,   const float* __restrict__ b2,
    const float* __restrict__ damping, const int* __restrict__ stepsPtr,
    float* __restrict__ out)
{
  extern __shared__ __align__(16) char smem[];
  unsigned* pw0  = (unsigned*)(smem + OFF_PW0);
  unsigned* pih1 = (unsigned*)(smem + OFF_PIH1);
  unsigned* phh1 = (unsigned*)(smem + OFF_PHH1);
  unsigned* pw1m = (unsigned*)(smem + OFF_PW1M);
  unsigned* h1p  = (unsigned*)(smem + OFF_H1P);
  unsigned* h2p  = (unsigned*)(smem + OFF_H2P);
  float*    win  = (float*)(smem + OFF_WIN);
  float*    w2s  = (float*)(smem + OFF_W2);
  float*    b1s  = (float*)(smem + OFF_B1S);

  const int tid  = threadIdx.x;
  const int wave = tid >> 6;
  const int lane = tid & 63;
  const int j    = lane;           // hidden unit owned by this lane
  const int b0   = blockIdx.x * BPB;
  const int mb0  = wave * BPW;

  // ---- pack the three 256x64 matrices to f16x2 [k2][j][g] ----
  for (int e = tid; e < 256 * 32; e += NTHR) {
    int r = e >> 5, c2 = e & 31;          // row of W, k-pair index
    int jj = r & 63, g = r >> 6;
    int dst = (c2 * 64 + jj) * 4 + g;
    const float* s0 = Whh0 + r * 64 + 2 * c2;
    pw0[dst]  = pack2(s0[0], s0[1]);
    const float* s1 = Wih1 + r * 64 + 2 * c2;
    pih1[dst] = pack2(s1[0], s1[1]);
    const float* s2 = Whh1 + r * 64 + 2 * c2;
    phh1[dst] = pack2(s2[0], s2[1]);
  }
  // MLP W1 [32][64] -> [k2][i]
  for (int e = tid; e < 32 * 32; e += NTHR) {
    int i = e >> 5, c2 = e & 31;
    pw1m[c2 * 32 + i] = pack2(W1[i * 64 + 2 * c2], W1[i * 64 + 2 * c2 + 1]);
  }
  if (tid < 32) { w2s[tid] = W2[tid]; b1s[tid] = b1[tid]; }
  // window init: win[t][mb] = x[b0+mb][t]
  for (int e = tid; e < BPB * TWIN; e += NTHR) {
    int mb = e / TWIN, t = e % TWIN;
    win[t * BPB + mb] = x[(b0 + mb) * TWIN + t];
  }

  // per-lane constants
  float bias0[4], wih0r[4], bias1[4];
  #pragma unroll
  for (int g = 0; g < 4; ++g) {
    bias0[g] = bih0[g * 64 + j] + bhh0[g * 64 + j];
    wih0r[g] = Wih0[g * 64 + j];
    bias1[g] = bih1[g * 64 + j] + bhh1[g * 64 + j];
  }
  const float alpha  = sigm(damping[0]);
  const int   nsteps = stepsPtr[0];
  const float b2v    = b2[0];

  __syncthreads();   // after this point: weights read-only, staging per-wave

  const int half = lane >> 5;   // MLP: which half-wave
  const int iM   = lane & 31;   // MLP: output neuron index
  float prevp[2];               // previous blended preds (m = half, half+2)

  for (int s = 0; s < nsteps; ++s) {
    // zero recurrent staging for this wave's batch columns
    if (lane < 32) {
      uint4 z = make_uint4(0, 0, 0, 0);
      *(uint4*)&h1p[lane * HSTR + mb0] = z;
      *(uint4*)&h2p[lane * HSTR + mb0] = z;
    }
    float c1[4] = {0, 0, 0, 0}, c2r[4] = {0, 0, 0, 0};

    for (int t = 0; t < TWIN; ++t) {
      int ph = s + t; if (ph >= TWIN) ph -= TWIN;
      float4 xw = *(const float4*)&win[ph * BPB + mb0];
      float xa[4] = {xw.x, xw.y, xw.z, xw.w};

      // ---- layer 0: gates = x_t*wih0 + h1 @ Whh0^T + b ----
      float a0[4][4];
      #pragma unroll
      for (int g = 0; g < 4; ++g)
        #pragma unroll
        for (int m = 0; m < 4; ++m)
          a0[g][m] = fmaf(xa[m], wih0r[g], bias0[g]);

      #pragma unroll 8
      for (int k2 = 0; k2 < 32; ++k2) {
        uint4 wv = *(const uint4*)&pw0[(k2 * 64 + j) * 4];   // per-lane
        uint4 hv = *(const uint4*)&h1p[k2 * HSTR + mb0];     // broadcast
        unsigned wg[4] = {wv.x, wv.y, wv.z, wv.w};
        unsigned hm[4] = {hv.x, hv.y, hv.z, hv.w};
        #pragma unroll
        for (int g = 0; g < 4; ++g)
          #pragma unroll
          for (int m = 0; m < 4; ++m)
            a0[g][m] = dot2(hm[m], wg[g], a0[g][m]);
      }

      float h1n[4];
      #pragma unroll
      for (int m = 0; m < 4; ++m) {
        float ig = sigm(a0[0][m]), fg = sigm(a0[1][m]);
        float gg = tanh_(a0[2][m]), og = sigm(a0[3][m]);
        float c  = fmaf(fg, c1[m], ig * gg);
        c1[m] = c;
        h1n[m] = og * tanh_(c);
      }
      // stage h1_t as f16 pairs (even lane packs (h[j], h[j+1]))
      {
        float hx0 = __shfl_xor(h1n[0], 1), hx1 = __shfl_xor(h1n[1], 1);
        float hx2 = __shfl_xor(h1n[2], 1), hx3 = __shfl_xor(h1n[3], 1);
        if (!(j & 1)) {
          uint4 u = make_uint4(pack2(h1n[0], hx0), pack2(h1n[1], hx1),
                               pack2(h1n[2], hx2), pack2(h1n[3], hx3));
          *(uint4*)&h1p[(j >> 1) * HSTR + mb0] = u;
        }
      }

      // ---- layer 1: gates = h1_t @ Wih1^T + h2 @ Whh1^T + b ----
      float a1[4][4];
      #pragma unroll
      for (int g = 0; g < 4; ++g)
        #pragma unroll
        for (int m = 0; m < 4; ++m)
          a1[g][m] = bias1[g];

      #pragma unroll 4
      for (int k2 = 0; k2 < 32; ++k2) {
        uint4 wi  = *(const uint4*)&pih1[(k2 * 64 + j) * 4];
        uint4 wh  = *(const uint4*)&phh1[(k2 * 64 + j) * 4];
        uint4 h1v = *(const uint4*)&h1p[k2 * HSTR + mb0];
        uint4 h2v = *(const uint4*)&h2p[k2 * HSTR + mb0];
        unsigned wig[4] = {wi.x, wi.y, wi.z, wi.w};
        unsigned whg[4] = {wh.x, wh.y, wh.z, wh.w};
        unsigned h1m[4] = {h1v.x, h1v.y, h1v.z, h1v.w};
        unsigned h2m[4] = {h2v.x, h2v.y, h2v.z, h2v.w};
        #pragma unroll
        for (int g = 0; g < 4; ++g)
          #pragma unroll
          for (int m = 0; m < 4; ++m) {
            float tv = dot2(h2m[m], whg[g], a1[g][m]);
            a1[g][m] = dot2(h1m[m], wig[g], tv);
          }
      }

      float h2n[4];
      #pragma unroll
      for (int m = 0; m < 4; ++m) {
        float ig = sigm(a1[0][m]), fg = sigm(a1[1][m]);
        float gg = tanh_(a1[2][m]), og = sigm(a1[3][m]);
        float c  = fmaf(fg, c2r[m], ig * gg);
        c2r[m] = c;
        h2n[m] = og * tanh_(c);
      }
      {
        float hx0 = __shfl_xor(h2n[0], 1), hx1 = __shfl_xor(h2n[1], 1);
        float hx2 = __shfl_xor(h2n[2], 1), hx3 = __shfl_xor(h2n[3], 1);
        if (!(j & 1)) {
          uint4 u = make_uint4(pack2(h2n[0], hx0), pack2(h2n[1], hx1),
                               pack2(h2n[2], hx2), pack2(h2n[3], hx3));
          *(uint4*)&h2p[(j >> 1) * HSTR + mb0] = u;
        }
      }
    } // t

    // ---- MLP head: pred = relu(h2 @ W1^T + b1) @ W2^T + b2 ----
    // lane (half, iM) accumulates y[iM] for batches m = half, half+2
    float acc[2] = { b1s[iM], b1s[iM] };
    #pragma unroll 8
    for (int k2 = 0; k2 < 32; ++k2) {
      unsigned wv = pw1m[k2 * 32 + iM];
      #pragma unroll
      for (int q = 0; q < 2; ++q) {
        unsigned hv = h2p[k2 * HSTR + mb0 + half + 2 * q];
        acc[q] = dot2(hv, wv, acc[q]);
      }
    }
    #pragma unroll
    for (int q = 0; q < 2; ++q) {
      float y = fmaxf(acc[q], 0.0f) * w2s[iM];
      #pragma unroll
      for (int mask = 1; mask <= 16; mask <<= 1)
        y += __shfl_xor(y, mask);           // sum over 32 neurons in-half
      float pr = y + b2v;
      float pd = (s == 0) ? pr
                          : fmaf(pr, 1.0f - alpha, prevp[q] * (alpha * 0.5f));
      prevp[q] = pd;
      if (iM == 0) {
        int m = half + 2 * q;
        int slot = s % TWIN;                // oldest slot -> new pred
        win[slot * BPB + mb0 + m] = pd;
        out[(long)(b0 + mb0 + m) * nsteps + s] = pd;
      }
    }
  } // s
}

extern "C" void kernel_launch(void* const* d_in, const int* in_sizes, int n_in,
                              void* d_out, int out_size, void* d_ws, size_t ws_size,
                              hipStream_t stream) {
  (void)in_sizes; (void)n_in; (void)out_size; (void)d_ws; (void)ws_size;
  hipFuncSetAttribute((const void*)lstm_forecast,
                      hipFuncAttributeMaxDynamicSharedMemorySize, SMEM_BYTES);
  lstm_forecast<<<NBLK, NTHR, SMEM_BYTES, stream>>>(
      (const float*)d_in[0],
      (const float*)d_in[1],  (const float*)d_in[2],
      (const float*)d_in[3],  (const float*)d_in[4],
      (const float*)d_in[5],  (const float*)d_in[6],
      (const float*)d_in[7],  (const float*)d_in[8],
      (const float*)d_in[9],  (const float*)d_in[10],
      (const float*)d_in[11], (const float*)d_in[12],
      (const float*)d_in[13], (const int*)d_in[14],
      (float*)d_out);
}

// Round 2
// 2345.755 us; speedup vs baseline: 1.7586x; 1.7586x over previous
//
#include <hip/hip_runtime.h>

// AutoregressiveForecaster R2: MFMA formulation.
// 2-layer LSTM(H=64) + MLP head, 20 autoregressive steps, 24-window, B=8192.
//
//  - 256 blocks x 128 threads (2 waves). Each wave owns a 16-batch tile (MFMA M).
//  - gates[16,256] = h[16,64] @ W^T via mfma_f32_16x16x32_f16, 16 n-tiles of 16
//    gates; L1 fuses ih+hh as K=128 (4 chained MFMA per tile).
//  - Weights pre-packed into per-lane B-fragments in LDS: frag(lane,tile,f) =
//    W[16*tile+(lane&15)][f*32+(lane>>4)*8 .. +7] as 8 f16 (one b128, lane-linear,
//    conflict-free). A-frags use the SAME k-mapping (correct for any bijection).
//  - D layout (verified): col=lane&15 (gate), row=(lane>>4)*4+reg (batch) ->
//    LSTM elementwise is lane-local; c-state in registers.
//  - h1/h2 staged per-wave in LDS f16 [16][80] (160B row stride, 16B-aligned).
//  - No barriers in the hot loop (per-wave staging; in-order DS per wave).

typedef _Float16 f16x8 __attribute__((ext_vector_type(8)));
typedef float f32x4 __attribute__((ext_vector_type(4)));

#define NBLK 256
#define NTHR 128
#define SRB  160        // h row stride in bytes (80 f16)
#define OFF_WF0 0       // Whh0 B-frags  [16 tiles][2 frags][64 lanes][16B] = 32KB
#define OFF_WF1 32768   // Wih1
#define OFF_WF2 65536   // Whh1
#define OFF_WFM 98304   // W1 (MLP)      [2][2][64][16B] = 4KB
#define OFF_H1  102400  // + wave*2560   [16][80] f16
#define OFF_H2  107520  // + wave*2560
#define OFF_WIN 112640  // + wave*1536   [24][16] f32
#define SMEM_BYTES 115712

__device__ __forceinline__ float sigm(float x) {
  float e = __builtin_amdgcn_exp2f(-1.44269504089f * x);
  return __builtin_amdgcn_rcpf(1.0f + e);
}
__device__ __forceinline__ float tanh_(float x) {
  float e = __builtin_amdgcn_exp2f(-2.88539008178f * x);
  return __builtin_amdgcn_rcpf(1.0f + e) * 2.0f - 1.0f;
}

__device__ __forceinline__ f32x4 mfma16(uint4 a, uint4 b, f32x4 c) {
  return __builtin_amdgcn_mfma_f32_16x16x32_f16(
      __builtin_bit_cast(f16x8, a), __builtin_bit_cast(f16x8, b), c, 0, 0, 0);
}

__device__ __forceinline__ uint4 pack8(const float* p) {
  union { uint4 u; _Float16 h[8]; } r;
  #pragma unroll
  for (int i = 0; i < 8; ++i) r.h[i] = (_Float16)p[i];
  return r.u;
}

__global__ __launch_bounds__(NTHR, 1) void lstm_forecast(
    const float* __restrict__ x,
    const float* __restrict__ Wih0, const float* __restrict__ Whh0,
    const float* __restrict__ bih0, const float* __restrict__ bhh0,
    const float* __restrict__ Wih1, const float* __restrict__ Whh1,
    const float* __restrict__ bih1, const float* __restrict__ bhh1,
    const float* __restrict__ W1,   const float* __restrict__ b1,
    const float* __restrict__ W2,   const float* __restrict__ b2,
    const float* __restrict__ damping, const int* __restrict__ stepsPtr,
    float* __restrict__ out)
{
  extern __shared__ __align__(16) char smem[];
  const int tid  = threadIdx.x;
  const int wave = tid >> 6;
  const int lane = tid & 63;
  const int cc   = lane & 15;   // D col / A row / B col index
  const int hi   = lane >> 4;   // k-group
  const int b0g  = blockIdx.x * 32 + wave * 16;

  uint4* wf0 = (uint4*)(smem + OFF_WF0);
  uint4* wf1 = (uint4*)(smem + OFF_WF1);
  uint4* wf2 = (uint4*)(smem + OFF_WF2);
  uint4* wfm = (uint4*)(smem + OFF_WFM);
  char*  h1c = smem + OFF_H1 + wave * 2560;
  char*  h2c = smem + OFF_H2 + wave * 2560;
  float* winw = (float*)(smem + OFF_WIN + wave * 1536);

  // ---- pack weight B-fragments (slot e = (n*2+f)*64 + lane) ----
  for (int e = tid; e < 2048; e += NTHR) {
    int l = e & 63, f = (e >> 6) & 1, n = e >> 7;
    int row = n * 16 + (l & 15);
    int col = f * 32 + (l >> 4) * 8;
    wf0[e] = pack8(Whh0 + row * 64 + col);
    wf1[e] = pack8(Wih1 + row * 64 + col);
    wf2[e] = pack8(Whh1 + row * 64 + col);
  }
  for (int e = tid; e < 256; e += NTHR) {
    int l = e & 63, f = (e >> 6) & 1, n = e >> 7;
    wfm[e] = pack8(W1 + (n * 16 + (l & 15)) * 64 + f * 32 + (l >> 4) * 8);
  }
  // window init: winw[t][b] = x[(b0g+b)*24 + t]
  for (int e = lane; e < 384; e += 64) {
    int b = e / 24, t = e % 24;
    winw[t * 16 + b] = x[(b0g + b) * 24 + t];
  }

  // per-lane constants (gate g = n*16 + cc)
  float bias0f[16], wih0f[16], bias1f[16];
  #pragma unroll
  for (int n = 0; n < 16; ++n) {
    int g = n * 16 + cc;
    bias0f[n] = bih0[g] + bhh0[g];
    wih0f[n]  = Wih0[g];
    bias1f[n] = bih1[g] + bhh1[g];
  }
  float w2v[2], b1v[2];
  #pragma unroll
  for (int n = 0; n < 2; ++n) { w2v[n] = W2[n * 16 + cc]; b1v[n] = b1[n * 16 + cc]; }
  const float alpha  = sigm(damping[0]);
  const int   nsteps = stepsPtr[0];
  const float b2v    = b2[0];

  __syncthreads();

  unsigned* h1u = (unsigned*)h1c;
  unsigned* h2u = (unsigned*)h2c;
  float prevp[4];

  for (int s = 0; s < nsteps; ++s) {
    // zero recurrent state
    for (int i = lane; i < 640; i += 64) { h1u[i] = 0; h2u[i] = 0; }
    float c1[4][4], c2s[4][4];
    #pragma unroll
    for (int q = 0; q < 4; ++q)
      #pragma unroll
      for (int r = 0; r < 4; ++r) { c1[q][r] = 0.0f; c2s[q][r] = 0.0f; }

    for (int t = 0; t < 24; ++t) {
      int ph = s + t; if (ph >= 24) ph -= 24;
      float xr[4];
      #pragma unroll
      for (int r = 0; r < 4; ++r) xr[r] = winw[ph * 16 + hi * 4 + r];

      // A-frags of h1_{t-1}, h2_{t-1}
      uint4 a1lo = *(uint4*)(h1c + cc * SRB + hi * 16);
      uint4 a1hi = *(uint4*)(h1c + cc * SRB + hi * 16 + 64);
      uint4 a2lo = *(uint4*)(h2c + cc * SRB + hi * 16);
      uint4 a2hi = *(uint4*)(h2c + cc * SRB + hi * 16 + 64);

      // ---- layer 0 ----
      float h1t[4][4];
      #pragma unroll
      for (int q = 0; q < 4; ++q) {
        f32x4 acc[4];
        #pragma unroll
        for (int tau = 0; tau < 4; ++tau) {
          int n = tau * 4 + q;
          f32x4 ai;
          #pragma unroll
          for (int r = 0; r < 4; ++r) ai[r] = fmaf(xr[r], wih0f[n], bias0f[n]);
          uint4 blo = wf0[(n * 2 + 0) * 64 + lane];
          uint4 bhi = wf0[(n * 2 + 1) * 64 + lane];
          acc[tau] = mfma16(a1lo, blo, ai);
          acc[tau] = mfma16(a1hi, bhi, acc[tau]);
        }
        #pragma unroll
        for (int r = 0; r < 4; ++r) {
          float ig = sigm(acc[0][r]), fg = sigm(acc[1][r]);
          float gg = tanh_(acc[2][r]), og = sigm(acc[3][r]);
          float cv = fmaf(fg, c1[q][r], ig * gg);
          c1[q][r] = cv;
          h1t[q][r] = og * tanh_(cv);
        }
      }
      // stage h1_t (f16 scalar stores, lane-local)
      #pragma unroll
      for (int q = 0; q < 4; ++q)
        #pragma unroll
        for (int r = 0; r < 4; ++r)
          *(_Float16*)(h1c + (hi * 4 + r) * SRB + (16 * q + cc) * 2) =
              (_Float16)h1t[q][r];
      // A-frags of h1_t
      uint4 atlo = *(uint4*)(h1c + cc * SRB + hi * 16);
      uint4 athi = *(uint4*)(h1c + cc * SRB + hi * 16 + 64);

      // ---- layer 1 (K=128: [h1_t | h2_{t-1}]) ----
      float h2t[4][4];
      #pragma unroll
      for (int q = 0; q < 4; ++q) {
        f32x4 acc[4];
        #pragma unroll
        for (int tau = 0; tau < 4; ++tau) {
          int n = tau * 4 + q;
          f32x4 ai;
          #pragma unroll
          for (int r = 0; r < 4; ++r) ai[r] = bias1f[n];
          uint4 bilo = wf1[(n * 2 + 0) * 64 + lane];
          uint4 bihi = wf1[(n * 2 + 1) * 64 + lane];
          uint4 bhlo = wf2[(n * 2 + 0) * 64 + lane];
          uint4 bhhi = wf2[(n * 2 + 1) * 64 + lane];
          acc[tau] = mfma16(atlo, bilo, ai);
          acc[tau] = mfma16(athi, bihi, acc[tau]);
          acc[tau] = mfma16(a2lo, bhlo, acc[tau]);
          acc[tau] = mfma16(a2hi, bhhi, acc[tau]);
        }
        #pragma unroll
        for (int r = 0; r < 4; ++r) {
          float ig = sigm(acc[0][r]), fg = sigm(acc[1][r]);
          float gg = tanh_(acc[2][r]), og = sigm(acc[3][r]);
          float cv = fmaf(fg, c2s[q][r], ig * gg);
          c2s[q][r] = cv;
          h2t[q][r] = og * tanh_(cv);
        }
      }
      #pragma unroll
      for (int q = 0; q < 4; ++q)
        #pragma unroll
        for (int r = 0; r < 4; ++r)
          *(_Float16*)(h2c + (hi * 4 + r) * SRB + (16 * q + cc) * 2) =
              (_Float16)h2t[q][r];
    } // t

    // ---- MLP head on h2_last ----
    uint4 hflo = *(uint4*)(h2c + cc * SRB + hi * 16);
    uint4 hfhi = *(uint4*)(h2c + cc * SRB + hi * 16 + 64);
    f32x4 am0, am1;
    #pragma unroll
    for (int r = 0; r < 4; ++r) { am0[r] = b1v[0]; am1[r] = b1v[1]; }
    am0 = mfma16(hflo, wfm[0 * 64 + lane], am0);
    am0 = mfma16(hfhi, wfm[1 * 64 + lane], am0);
    am1 = mfma16(hflo, wfm[2 * 64 + lane], am1);
    am1 = mfma16(hfhi, wfm[3 * 64 + lane], am1);

    int slot = s % 24;
    #pragma unroll
    for (int r = 0; r < 4; ++r) {
      float y = fmaxf(am0[r], 0.0f) * w2v[0] + fmaxf(am1[r], 0.0f) * w2v[1];
      y += __shfl_xor(y, 1);
      y += __shfl_xor(y, 2);
      y += __shfl_xor(y, 4);
      y += __shfl_xor(y, 8);
      float pr = y + b2v;
      float pd = (s == 0) ? pr
                          : fmaf(pr, 1.0f - alpha, prevp[r] * (alpha * 0.5f));
      prevp[r] = pd;
      if (cc == 0) {
        winw[slot * 16 + hi * 4 + r] = pd;
        out[(long)(b0g + hi * 4 + r) * nsteps + s] = pd;
      }
    }
  } // s
}

extern "C" void kernel_launch(void* const* d_in, const int* in_sizes, int n_in,
                              void* d_out, int out_size, void* d_ws, size_t ws_size,
                              hipStream_t stream) {
  (void)in_sizes; (void)n_in; (void)out_size; (void)d_ws; (void)ws_size;
  hipFuncSetAttribute((const void*)lstm_forecast,
                      hipFuncAttributeMaxDynamicSharedMemorySize, SMEM_BYTES);
  lstm_forecast<<<NBLK, NTHR, SMEM_BYTES, stream>>>(
      (const float*)d_in[0],
      (const float*)d_in[1],  (const float*)d_in[2],
      (const float*)d_in[3],  (const float*)d_in[4],
      (const float*)d_in[5],  (const float*)d_in[6],
      (const float*)d_in[7],  (const float*)d_in[8],
      (const float*)d_in[9],  (const float*)d_in[10],
      (const float*)d_in[11], (const float*)d_in[12],
      (const float*)d_in[13], (const int*)d_in[14],
      (float*)d_out);
}

// Round 3
// 720.082 us; speedup vs baseline: 5.7287x; 3.2576x over previous
//
#include <hip/hip_runtime.h>

// AutoregressiveForecaster R3: cooperative 4-wave blocks, weights in VGPRs.
// 2-layer LSTM(H=64) + MLP head, 20 autoregressive steps, 24-window, B=8192.
//
//  - 512 blocks x 256 threads (4 waves). Block owns ONE 16-batch MFMA M-tile.
//  - Wave w computes gate-tiles n = {w, w+4, w+8, w+12} = gates i,f,g,o of
//    hidden units [16w, 16w+16): elementwise stays lane-local (c in regs).
//  - Weight B-fragments live in VGPRs (3 matrices x 4 gt x 2 frags = 24 uint4).
//    NO weight LDS traffic in the hot loop.
//  - h1/h2 exchanged via tiny LDS ([16][80] f16 each); 2 barriers/timestep.
//  - ~7KB LDS/block -> 2 blocks/CU (8 waves/CU), cross-block latency hiding.
//  - Fragment k-mapping conventions identical to R2 (verified): A-frag read at
//    row cc, bytes hi*16 (+64 for f=1); B-pack W[n*16+cc][f*32+hi*8 .. +7].

typedef _Float16 f16x8 __attribute__((ext_vector_type(8)));
typedef float f32x4 __attribute__((ext_vector_type(4)));

#define NBLK 512
#define NTHR 256
#define SRB  160   // h row stride bytes (80 f16)

__device__ __forceinline__ float sigm(float x) {
  float e = __builtin_amdgcn_exp2f(-1.44269504089f * x);
  return __builtin_amdgcn_rcpf(1.0f + e);
}
__device__ __forceinline__ float tanh_(float x) {
  float e = __builtin_amdgcn_exp2f(-2.88539008178f * x);
  return __builtin_amdgcn_rcpf(1.0f + e) * 2.0f - 1.0f;
}
__device__ __forceinline__ f32x4 mfma16(uint4 a, uint4 b, f32x4 c) {
  return __builtin_amdgcn_mfma_f32_16x16x32_f16(
      __builtin_bit_cast(f16x8, a), __builtin_bit_cast(f16x8, b), c, 0, 0, 0);
}
__device__ __forceinline__ uint4 pack8(const float* p) {
  union { uint4 u; _Float16 h[8]; } r;
  #pragma unroll
  for (int i = 0; i < 8; ++i) r.h[i] = (_Float16)p[i];
  return r.u;
}

__global__ __launch_bounds__(NTHR, 2) void lstm_forecast(
    const float* __restrict__ x,
    const float* __restrict__ Wih0, const float* __restrict__ Whh0,
    const float* __restrict__ bih0, const float* __restrict__ bhh0,
    const float* __restrict__ Wih1, const float* __restrict__ Whh1,
    const float* __restrict__ bih1, const float* __restrict__ bhh1,
    const float* __restrict__ W1,   const float* __restrict__ b1,
    const float* __restrict__ W2,   const float* __restrict__ b2,
    const float* __restrict__ damping, const int* __restrict__ stepsPtr,
    float* __restrict__ out)
{
  __shared__ __align__(16) _Float16 h1s[16 * 80];   // 2560 B
  __shared__ __align__(16) _Float16 h2s[16 * 80];   // 2560 B
  __shared__ __align__(16) float    win[24 * 16];   // 1536 B
  __shared__ __align__(16) float    pm[2][16];

  const int tid  = threadIdx.x;
  const int wave = tid >> 6;
  const int lane = tid & 63;
  const int cc   = lane & 15;
  const int hi   = lane >> 4;
  const int b0g  = blockIdx.x * 16;
  char* h1c = (char*)h1s;
  char* h2c = (char*)h2s;

  // ---- weight B-fragments into VGPRs ----
  uint4 wB0[4][2], wB1[4][2], wB2[4][2];
  #pragma unroll
  for (int gt = 0; gt < 4; ++gt) {
    int row = (wave + 4 * gt) * 16 + cc;
    #pragma unroll
    for (int f = 0; f < 2; ++f) {
      int col = f * 32 + hi * 8;
      wB0[gt][f] = pack8(Whh0 + row * 64 + col);
      wB1[gt][f] = pack8(Wih1 + row * 64 + col);
      wB2[gt][f] = pack8(Whh1 + row * 64 + col);
    }
  }
  // MLP fragments (waves 0,1 use them; 2,3 load duplicates harmlessly)
  uint4 wM[2];
  {
    int row = (wave & 1) * 16 + cc;
    wM[0] = pack8(W1 + row * 64 + 0 * 32 + hi * 8);
    wM[1] = pack8(W1 + row * 64 + 1 * 32 + hi * 8);
  }
  const float w2v  = W2[(wave & 1) * 16 + cc];
  const float b1vv = b1[(wave & 1) * 16 + cc];

  // per-lane gate constants (gate g = (wave+4*gt)*16 + cc)
  float bias0v[4], wih0v[4], bias1v[4];
  #pragma unroll
  for (int gt = 0; gt < 4; ++gt) {
    int g = (wave + 4 * gt) * 16 + cc;
    bias0v[gt] = bih0[g] + bhh0[g];
    wih0v[gt]  = Wih0[g];
    bias1v[gt] = bih1[g] + bhh1[g];
  }
  const float alpha  = sigm(damping[0]);
  const int   nsteps = stepsPtr[0];
  const float b2v    = b2[0];

  // window init: win[t*16+b] = x[(b0g+b)*24 + t]
  for (int e = tid; e < 384; e += NTHR) {
    int b = e & 15, t = e >> 4;
    win[t * 16 + b] = x[(b0g + b) * 24 + t];
  }

  float prevp = 0.0f;  // wave 0, lanes 0..15

  for (int s = 0; s < nsteps; ++s) {
    // zero recurrent state (both h buffers)
    {
      unsigned* h1u = (unsigned*)h1s;
      unsigned* h2u = (unsigned*)h2s;
      for (int e = tid; e < 1280; e += NTHR) {
        if (e < 640) h1u[e] = 0; else h2u[e - 640] = 0;
      }
    }
    __syncthreads();

    uint4 a1lo = make_uint4(0, 0, 0, 0), a1hi = make_uint4(0, 0, 0, 0);
    float c1[4] = {0, 0, 0, 0}, c2s[4] = {0, 0, 0, 0};

    for (int t = 0; t < 24; ++t) {
      int ph = s + t; if (ph >= 24) ph -= 24;
      float xr[4];
      #pragma unroll
      for (int r = 0; r < 4; ++r) xr[r] = win[ph * 16 + hi * 4 + r];
      // h2_{t-1} A-frags
      uint4 a2lo = *(uint4*)(h2c + cc * SRB + hi * 16);
      uint4 a2hi = *(uint4*)(h2c + cc * SRB + hi * 16 + 64);

      // ---- layer 0: K=64 over h1_{t-1} ----
      f32x4 acc[4];
      #pragma unroll
      for (int gt = 0; gt < 4; ++gt) {
        f32x4 ai;
        #pragma unroll
        for (int r = 0; r < 4; ++r) ai[r] = fmaf(xr[r], wih0v[gt], bias0v[gt]);
        acc[gt] = mfma16(a1lo, wB0[gt][0], ai);
        acc[gt] = mfma16(a1hi, wB0[gt][1], acc[gt]);
      }
      float h1t[4];
      #pragma unroll
      for (int r = 0; r < 4; ++r) {
        float ig = sigm(acc[0][r]), fg = sigm(acc[1][r]);
        float gg = tanh_(acc[2][r]), og = sigm(acc[3][r]);
        float cv = fmaf(fg, c1[r], ig * gg);
        c1[r] = cv;
        h1t[r] = og * tanh_(cv);
      }
      // stage h1_t slice: batch hi*4+r, hidden wave*16+cc
      #pragma unroll
      for (int r = 0; r < 4; ++r)
        *(_Float16*)(h1c + (hi * 4 + r) * SRB + (wave * 16 + cc) * 2) =
            (_Float16)h1t[r];
      __syncthreads();

      // h1_t A-frags
      uint4 atlo = *(uint4*)(h1c + cc * SRB + hi * 16);
      uint4 athi = *(uint4*)(h1c + cc * SRB + hi * 16 + 64);

      // ---- layer 1: K=128 over [h1_t | h2_{t-1}] ----
      #pragma unroll
      for (int gt = 0; gt < 4; ++gt) {
        f32x4 ai;
        #pragma unroll
        for (int r = 0; r < 4; ++r) ai[r] = bias1v[gt];
        f32x4 tv = mfma16(atlo, wB1[gt][0], ai);
        tv = mfma16(athi, wB1[gt][1], tv);
        tv = mfma16(a2lo, wB2[gt][0], tv);
        acc[gt] = mfma16(a2hi, wB2[gt][1], tv);
      }
      float h2t[4];
      #pragma unroll
      for (int r = 0; r < 4; ++r) {
        float ig = sigm(acc[0][r]), fg = sigm(acc[1][r]);
        float gg = tanh_(acc[2][r]), og = sigm(acc[3][r]);
        float cv = fmaf(fg, c2s[r], ig * gg);
        c2s[r] = cv;
        h2t[r] = og * tanh_(cv);
      }
      #pragma unroll
      for (int r = 0; r < 4; ++r)
        *(_Float16*)(h2c + (hi * 4 + r) * SRB + (wave * 16 + cc) * 2) =
            (_Float16)h2t[r];
      a1lo = atlo; a1hi = athi;   // carry h1_t frags to next t
      __syncthreads();
    } // t

    // ---- MLP head on h2_last (waves 0,1 compute the two 16-neuron tiles) ----
    uint4 hflo = *(uint4*)(h2c + cc * SRB + hi * 16);
    uint4 hfhi = *(uint4*)(h2c + cc * SRB + hi * 16 + 64);
    if (wave < 2) {
      f32x4 am;
      #pragma unroll
      for (int r = 0; r < 4; ++r) am[r] = b1vv;
      am = mfma16(hflo, wM[0], am);
      am = mfma16(hfhi, wM[1], am);
      float yp[4];
      #pragma unroll
      for (int r = 0; r < 4; ++r) yp[r] = fmaxf(am[r], 0.0f) * w2v;
      #pragma unroll
      for (int mask = 1; mask <= 8; mask <<= 1) {
        #pragma unroll
        for (int r = 0; r < 4; ++r) yp[r] += __shfl_xor(yp[r], mask);
      }
      if (cc == 0) {
        #pragma unroll
        for (int r = 0; r < 4; ++r) pm[wave][hi * 4 + r] = yp[r];
      }
    }
    __syncthreads();

    if (wave == 0 && lane < 16) {
      float y = pm[0][lane] + pm[1][lane] + b2v;
      float pd = (s == 0) ? y : fmaf(y, 1.0f - alpha, prevp * (alpha * 0.5f));
      prevp = pd;
      win[(s % 24) * 16 + lane] = pd;
      out[(long)(b0g + lane) * nsteps + s] = pd;
    }
    // next-iteration zeroing provides the barrier before window reads
  } // s
}

extern "C" void kernel_launch(void* const* d_in, const int* in_sizes, int n_in,
                              void* d_out, int out_size, void* d_ws, size_t ws_size,
                              hipStream_t stream) {
  (void)in_sizes; (void)n_in; (void)out_size; (void)d_ws; (void)ws_size;
  lstm_forecast<<<NBLK, NTHR, 0, stream>>>(
      (const float*)d_in[0],
      (const float*)d_in[1],  (const float*)d_in[2],
      (const float*)d_in[3],  (const float*)d_in[4],
      (const float*)d_in[5],  (const float*)d_in[6],
      (const float*)d_in[7],  (const float*)d_in[8],
      (const float*)d_in[9],  (const float*)d_in[10],
      (const float*)d_in[11], (const float*)d_in[12],
      (const float*)d_in[13], (const int*)d_in[14],
      (float*)d_out);
}

// Round 4
// 640.214 us; speedup vs baseline: 6.4434x; 1.1248x over previous
//
#include <hip/hip_runtime.h>

// AutoregressiveForecaster R4: layer-pipelined, 1 barrier/timestep.
// 2-layer LSTM(H=64) + MLP head, 20 autoregressive steps, 24-window, B=8192.
//
//  - 512 blocks x 256 threads (4 waves), block owns one 16-batch MFMA M-tile.
//  - Wave w owns gate-tiles {w, w+4, w+8, w+12} = gates i,f,g,o of hidden
//    units [16w,16w+16) -> elementwise lane-local, c-state in registers.
//  - PIPELINED: between one barrier pair, compute L1(t) (needs h1(t),h2(t-1))
//    and L0(t+1) (needs h1(t), x(t+1)) -> 2 independent MFMA+elementwise
//    chains, 1 barrier/timestep. h1/h2 staging ping-pong buffered (race-free).
//  - Weights pre-scaled by log2(e) (2*log2(e) for tanh-gate rows): exp2 args
//    come straight out of MFMA acc (neg is a free modifier). L1 bias folded
//    into f32x4 MFMA C-init constant.
//  - Weight B-fragments in VGPRs; frag conventions as R2/R3 (verified).

typedef _Float16 f16x8 __attribute__((ext_vector_type(8)));
typedef float f32x4 __attribute__((ext_vector_type(4)));

#define NBLK 512
#define NTHR 256
#define SRB  160   // h row stride bytes (80 f16)

__device__ __forceinline__ float sigm(float x) {
  float e = __builtin_amdgcn_exp2f(-1.44269504089f * x);
  return __builtin_amdgcn_rcpf(1.0f + e);
}
__device__ __forceinline__ f32x4 mfma16(uint4 a, uint4 b, f32x4 c) {
  return __builtin_amdgcn_mfma_f32_16x16x32_f16(
      __builtin_bit_cast(f16x8, a), __builtin_bit_cast(f16x8, b), c, 0, 0, 0);
}
__device__ __forceinline__ uint4 pack8s(const float* p, float s) {
  union { uint4 u; _Float16 h[8]; } r;
  #pragma unroll
  for (int i = 0; i < 8; ++i) r.h[i] = (_Float16)(p[i] * s);
  return r.u;
}

__global__ __launch_bounds__(NTHR, 2) void lstm_forecast(
    const float* __restrict__ x,
    const float* __restrict__ Wih0, const float* __restrict__ Whh0,
    const float* __restrict__ bih0, const float* __restrict__ bhh0,
    const float* __restrict__ Wih1, const float* __restrict__ Whh1,
    const float* __restrict__ bih1, const float* __restrict__ bhh1,
    const float* __restrict__ W1,   const float* __restrict__ b1,
    const float* __restrict__ W2,   const float* __restrict__ b2,
    const float* __restrict__ damping, const int* __restrict__ stepsPtr,
    float* __restrict__ out)
{
  __shared__ __align__(16) _Float16 h1s[2][16 * 80];
  __shared__ __align__(16) _Float16 h2s[2][16 * 80];
  __shared__ __align__(16) float    win[24 * 16];
  __shared__ __align__(16) float    pm[2][16];

  const int tid  = threadIdx.x;
  const int wave = tid >> 6;
  const int lane = tid & 63;
  const int cc   = lane & 15;
  const int hi   = lane >> 4;
  const int b0g  = blockIdx.x * 16;

  const float LOG2E = 1.44269504089f;

  // ---- weight B-fragments into VGPRs (pre-scaled; gt: 0=i,1=f,2=g,3=o) ----
  uint4 wB0[4][2], wB1[4][2], wB2[4][2];
  float bias0v[4], wih0v[4];
  f32x4 bi1[4];
  #pragma unroll
  for (int gt = 0; gt < 4; ++gt) {
    float sc = (gt == 2) ? 2.0f * LOG2E : LOG2E;
    int row = (wave + 4 * gt) * 16 + cc;
    #pragma unroll
    for (int f = 0; f < 2; ++f) {
      int col = f * 32 + hi * 8;
      wB0[gt][f] = pack8s(Whh0 + row * 64 + col, sc);
      wB1[gt][f] = pack8s(Wih1 + row * 64 + col, sc);
      wB2[gt][f] = pack8s(Whh1 + row * 64 + col, sc);
    }
    bias0v[gt] = (bih0[row] + bhh0[row]) * sc;
    wih0v[gt]  = Wih0[row] * sc;
    float b1c  = (bih1[row] + bhh1[row]) * sc;
    #pragma unroll
    for (int r = 0; r < 4; ++r) bi1[gt][r] = b1c;
  }
  // MLP fragments (unscaled)
  uint4 wM[2];
  {
    int row = (wave & 1) * 16 + cc;
    wM[0] = pack8s(W1 + row * 64 + hi * 8, 1.0f);
    wM[1] = pack8s(W1 + row * 64 + 32 + hi * 8, 1.0f);
  }
  const float w2v  = W2[(wave & 1) * 16 + cc];
  const float b1vv = b1[(wave & 1) * 16 + cc];
  const float alpha  = sigm(damping[0]);
  const int   nsteps = stepsPtr[0];
  const float b2v    = b2[0];

  // window init: win[t*16+b] = x[(b0g+b)*24 + t]
  for (int e = tid; e < 384; e += NTHR) {
    int b = e & 15, t = e >> 4;
    win[t * 16 + b] = x[(b0g + b) * 24 + t];
  }
  __syncthreads();

  float prevp = 0.0f;

  for (int s = 0; s < nsteps; ++s) {
    float c1[4] = {0, 0, 0, 0}, c2s[4] = {0, 0, 0, 0};

    // ---- prologue: L0(0) = elementwise only (h1(-1)=0) ----
    {
      float4 xw = *(const float4*)&win[(s % 24) * 16 + hi * 4];
      float xr[4] = {xw.x, xw.y, xw.z, xw.w};
      #pragma unroll
      for (int r = 0; r < 4; ++r) {
        float a0 = fmaf(xr[r], wih0v[0], bias0v[0]);
        float a1 = fmaf(xr[r], wih0v[1], bias0v[1]);
        float a2 = fmaf(xr[r], wih0v[2], bias0v[2]);
        float a3 = fmaf(xr[r], wih0v[3], bias0v[3]);
        float ig = __builtin_amdgcn_rcpf(1.0f + __builtin_amdgcn_exp2f(-a0));
        float fg = __builtin_amdgcn_rcpf(1.0f + __builtin_amdgcn_exp2f(-a1));
        float gg = __builtin_amdgcn_rcpf(1.0f + __builtin_amdgcn_exp2f(-a2)) * 2.0f - 1.0f;
        float og = __builtin_amdgcn_rcpf(1.0f + __builtin_amdgcn_exp2f(-a3));
        float cv = fmaf(fg, c1[r], ig * gg);
        c1[r] = cv;
        float e2 = __builtin_amdgcn_exp2f(-2.88539008178f * cv);
        float hv = og * (__builtin_amdgcn_rcpf(1.0f + e2) * 2.0f - 1.0f);
        *(_Float16*)((char*)h1s[0] + (hi * 4 + r) * SRB + (wave * 16 + cc) * 2) =
            (_Float16)hv;
      }
    }
    __syncthreads();
    uint4 a1lo = *(uint4*)((char*)h1s[0] + cc * SRB + hi * 16);
    uint4 a1hi = *(uint4*)((char*)h1s[0] + cc * SRB + hi * 16 + 64);
    uint4 a2lo = make_uint4(0, 0, 0, 0), a2hi = make_uint4(0, 0, 0, 0);

    // ---- main pipelined loop: iteration t computes L1(t) and L0(t+1) ----
    for (int t = 0; t < 23; ++t) {
      int pb = (t + 1) & 1;
      int ph = s + t + 1; if (ph >= 24) ph -= 24;
      float4 xw = *(const float4*)&win[ph * 16 + hi * 4];
      float xr[4] = {xw.x, xw.y, xw.z, xw.w};

      // MFMA: L1(t) [K=128 over h1(t)|h2(t-1)] and L0(t+1) [K=64 over h1(t)]
      f32x4 acc1[4], acc0[4];
      #pragma unroll
      for (int gt = 0; gt < 4; ++gt) {
        f32x4 tv = mfma16(a1lo, wB1[gt][0], bi1[gt]);
        tv = mfma16(a1hi, wB1[gt][1], tv);
        tv = mfma16(a2lo, wB2[gt][0], tv);
        acc1[gt] = mfma16(a2hi, wB2[gt][1], tv);
      }
      #pragma unroll
      for (int gt = 0; gt < 4; ++gt) {
        f32x4 ai;
        #pragma unroll
        for (int r = 0; r < 4; ++r) ai[r] = fmaf(xr[r], wih0v[gt], bias0v[gt]);
        f32x4 tv = mfma16(a1lo, wB0[gt][0], ai);
        acc0[gt] = mfma16(a1hi, wB0[gt][1], tv);
      }

      // elementwise L1 -> h2(t), L0 -> h1(t+1); stage into buffer pb
      #pragma unroll
      for (int r = 0; r < 4; ++r) {
        float ig = __builtin_amdgcn_rcpf(1.0f + __builtin_amdgcn_exp2f(-acc1[0][r]));
        float fg = __builtin_amdgcn_rcpf(1.0f + __builtin_amdgcn_exp2f(-acc1[1][r]));
        float gg = __builtin_amdgcn_rcpf(1.0f + __builtin_amdgcn_exp2f(-acc1[2][r])) * 2.0f - 1.0f;
        float og = __builtin_amdgcn_rcpf(1.0f + __builtin_amdgcn_exp2f(-acc1[3][r]));
        float cv = fmaf(fg, c2s[r], ig * gg);
        c2s[r] = cv;
        float e2 = __builtin_amdgcn_exp2f(-2.88539008178f * cv);
        float hv = og * (__builtin_amdgcn_rcpf(1.0f + e2) * 2.0f - 1.0f);
        *(_Float16*)((char*)h2s[pb] + (hi * 4 + r) * SRB + (wave * 16 + cc) * 2) =
            (_Float16)hv;
      }
      #pragma unroll
      for (int r = 0; r < 4; ++r) {
        float ig = __builtin_amdgcn_rcpf(1.0f + __builtin_amdgcn_exp2f(-acc0[0][r]));
        float fg = __builtin_amdgcn_rcpf(1.0f + __builtin_amdgcn_exp2f(-acc0[1][r]));
        float gg = __builtin_amdgcn_rcpf(1.0f + __builtin_amdgcn_exp2f(-acc0[2][r])) * 2.0f - 1.0f;
        float og = __builtin_amdgcn_rcpf(1.0f + __builtin_amdgcn_exp2f(-acc0[3][r]));
        float cv = fmaf(fg, c1[r], ig * gg);
        c1[r] = cv;
        float e2 = __builtin_amdgcn_exp2f(-2.88539008178f * cv);
        float hv = og * (__builtin_amdgcn_rcpf(1.0f + e2) * 2.0f - 1.0f);
        *(_Float16*)((char*)h1s[pb] + (hi * 4 + r) * SRB + (wave * 16 + cc) * 2) =
            (_Float16)hv;
      }
      __syncthreads();
      a1lo = *(uint4*)((char*)h1s[pb] + cc * SRB + hi * 16);
      a1hi = *(uint4*)((char*)h1s[pb] + cc * SRB + hi * 16 + 64);
      a2lo = *(uint4*)((char*)h2s[pb] + cc * SRB + hi * 16);
      a2hi = *(uint4*)((char*)h2s[pb] + cc * SRB + hi * 16 + 64);
    } // t

    // ---- epilogue: L1(23) ----
    {
      f32x4 acc1[4];
      #pragma unroll
      for (int gt = 0; gt < 4; ++gt) {
        f32x4 tv = mfma16(a1lo, wB1[gt][0], bi1[gt]);
        tv = mfma16(a1hi, wB1[gt][1], tv);
        tv = mfma16(a2lo, wB2[gt][0], tv);
        acc1[gt] = mfma16(a2hi, wB2[gt][1], tv);
      }
      #pragma unroll
      for (int r = 0; r < 4; ++r) {
        float ig = __builtin_amdgcn_rcpf(1.0f + __builtin_amdgcn_exp2f(-acc1[0][r]));
        float fg = __builtin_amdgcn_rcpf(1.0f + __builtin_amdgcn_exp2f(-acc1[1][r]));
        float gg = __builtin_amdgcn_rcpf(1.0f + __builtin_amdgcn_exp2f(-acc1[2][r])) * 2.0f - 1.0f;
        float og = __builtin_amdgcn_rcpf(1.0f + __builtin_amdgcn_exp2f(-acc1[3][r]));
        float cv = fmaf(fg, c2s[r], ig * gg);
        float e2 = __builtin_amdgcn_exp2f(-2.88539008178f * cv);
        float hv = og * (__builtin_amdgcn_rcpf(1.0f + e2) * 2.0f - 1.0f);
        *(_Float16*)((char*)h2s[0] + (hi * 4 + r) * SRB + (wave * 16 + cc) * 2) =
            (_Float16)hv;
      }
    }
    __syncthreads();

    // ---- MLP head on h2(23) (waves 0,1) ----
    if (wave < 2) {
      uint4 hflo = *(uint4*)((char*)h2s[0] + cc * SRB + hi * 16);
      uint4 hfhi = *(uint4*)((char*)h2s[0] + cc * SRB + hi * 16 + 64);
      f32x4 am;
      #pragma unroll
      for (int r = 0; r < 4; ++r) am[r] = b1vv;
      am = mfma16(hflo, wM[0], am);
      am = mfma16(hfhi, wM[1], am);
      float yp[4];
      #pragma unroll
      for (int r = 0; r < 4; ++r) yp[r] = fmaxf(am[r], 0.0f) * w2v;
      #pragma unroll
      for (int mask = 1; mask <= 8; mask <<= 1) {
        #pragma unroll
        for (int r = 0; r < 4; ++r) yp[r] += __shfl_xor(yp[r], mask);
      }
      if (cc == 0) {
        #pragma unroll
        for (int r = 0; r < 4; ++r) pm[wave][hi * 4 + r] = yp[r];
      }
    }
    __syncthreads();

    if (wave == 0 && lane < 16) {
      float y = pm[0][lane] + pm[1][lane] + b2v;
      float pd = (s == 0) ? y : fmaf(y, 1.0f - alpha, prevp * (alpha * 0.5f));
      prevp = pd;
      win[(s % 24) * 16 + lane] = pd;
      out[(long)(b0g + lane) * nsteps + s] = pd;
    }
    __syncthreads();
  } // s
}

extern "C" void kernel_launch(void* const* d_in, const int* in_sizes, int n_in,
                              void* d_out, int out_size, void* d_ws, size_t ws_size,
                              hipStream_t stream) {
  (void)in_sizes; (void)n_in; (void)out_size; (void)d_ws; (void)ws_size;
  lstm_forecast<<<NBLK, NTHR, 0, stream>>>(
      (const float*)d_in[0],
      (const float*)d_in[1],  (const float*)d_in[2],
      (const float*)d_in[3],  (const float*)d_in[4],
      (const float*)d_in[5],  (const float*)d_in[6],
      (const float*)d_in[7],  (const float*)d_in[8],
      (const float*)d_in[9],  (const float*)d_in[10],
      (const float*)d_in[11], (const float*)d_in[12],
      (const float*)d_in[13], (const int*)d_in[14],
      (float*)d_out);
}